// Round 4
// baseline (82.118 us; speedup 1.0000x reference)
//
#include <hip/hip_runtime.h>
#include <hip/hip_bf16.h>

typedef __bf16 bf16x8 __attribute__((ext_vector_type(8)));
typedef float f32x4 __attribute__((ext_vector_type(4)));

#define NUM_TEAMS 100000
#define NUM_MATCHES 1000000
#define LOG2E 1.4426950408889634f
#define NWG 6250            // 3125 32-team tiles x 2 hcol-halves (100000 = 32*3125 exact)
#define XQ 781              // NWG/8
#define XR 2                // NWG%8

__device__ __forceinline__ unsigned short f2bf(float x) {
    __hip_bfloat16 h = __float2bfloat16(x);
    return reinterpret_cast<unsigned short&>(h);
}
// single-instruction packed f32x2 -> bf16x2. No builtin on gfx950 (m240) -> asm.
__device__ __forceinline__ unsigned int cvtpk(float a, float b) {
    unsigned int r;
    asm("v_cvt_pk_bf16_f32 %0, %1, %2" : "=v"(r) : "v"(a), "v"(b));
    return r;
}
__device__ __forceinline__ float exp2_(float x) {
    float r; asm("v_exp_f32 %0, %1" : "=v"(r) : "v"(x)); return r;
}
__device__ __forceinline__ float rcp_(float x) {
    float r; asm("v_rcp_f32 %0, %1" : "=v"(r) : "v"(x)); return r;
}
// async global->LDS, 16B per lane. Dest = wave-uniform base + lane*16 (m104/m108).
__device__ __forceinline__ void load_lds16(const float* g, float* l) {
    __builtin_amdgcn_global_load_lds(
        (const __attribute__((address_space(1))) void*)g,
        (__attribute__((address_space(3))) void*)l, 16, 0, 0);
}

// ---------------- prep: pack W fragment-major bf16; biases pre-scaled by log2e ----------------
// Wpk u16 index = G*16384 + gate*4096 + ks*512 + l4*128 + l15*8 + e
//   holds W[row = gate*128 + G*16 + l15][k = ks*32 + l4*8 + e]  (W = [W_ih | W_hh])
__global__ __launch_bounds__(256) void prep_kernel(
    const float* __restrict__ W_ih, const float* __restrict__ W_hh,
    const float* __restrict__ b_ih, const float* __restrict__ b_hh,
    unsigned short* __restrict__ Wpk, float* __restrict__ biasc)
{
    int gid = blockIdx.x * 256 + threadIdx.x;   // 131072 bf16 elements
    int e = gid & 7;
    int chunk = gid >> 3;                        // 16B chunk id
    int l15 = chunk & 15;
    int l4 = (chunk >> 4) & 3;
    int rest = chunk >> 6;
    int ks = rest & 7;
    int gate = (rest >> 3) & 3;
    int G = rest >> 5;
    int row = gate * 128 + G * 16 + l15;
    int k = ks * 32 + l4 * 8 + e;
    float v = (k < 128) ? W_ih[row * 128 + k] : W_hh[row * 128 + (k - 128)];
    Wpk[gid] = f2bf(v);
    if (gid < 512) {
        float b = b_ih[gid] + b_hh[gid];
        float scale = ((gid >> 7) == 2) ? (2.0f * LOG2E) : (-LOG2E);
        biasc[gid] = b * scale;
    }
}

// ---------------- LSTM + fused partial proj ----------------
// Occupancy-first redesign. Tile: 32 teams x 64 hcols (half ch) x 4 gates.
// acc 32 AGPR + ~60 arch VGPR (2-pass reg-lean staging) <= 102 -> 5 waves/SIMD
// (__launch_bounds__(256,5)). LDS 27.8 KB -> 5 blocks/CU co-resident.
// => 20 waves/CU in 5 INDEPENDENT blocks (vs round-0's 16/4) — the only lever
// that has moved this latency-bound kernel across rounds 0-3.
// cx staged via global_load_lds (zero VGPR) into group-padded LDS: 8 groups of
// 4 rows, 1040 B apart (1 KB payload + 16 B pad) -> linear 1 KB async writes,
// act-phase reads land 2-way max (260-word group stride -> 4-bank shift).
__global__ __launch_bounds__(256, 5) void lstm_kernel(
    const float* __restrict__ inputs, const float* __restrict__ hx,
    const float* __restrict__ cx, const unsigned short* __restrict__ Wpk,
    const float* __restrict__ biasc, const float* __restrict__ W_out,
    float* __restrict__ projP)
{
    __shared__ __align__(16) unsigned short Abf[32 * 256];  // 16 KB; reused as Hf f32[32][64]
    __shared__ __align__(16) float cxl[8 * 260];            // 8.3 KB grouped-pad cx tile
    __shared__ float Wlds[768];
    const int tid = threadIdx.x;

    // bijective chunked XCD swizzle: halves (2t,2t+1) land on the same XCD
    const int orig = blockIdx.x;
    const int xcd = orig & 7, idx = orig >> 3;
    const int wgid = (xcd < XR ? xcd * (XQ + 1) : XR * (XQ + 1) + (xcd - XR) * XQ) + idx;
    const int tile = wgid >> 1, ch = wgid & 1;
    const int brow = tile * 32;                      // 100000 % 32 == 0: no clamps anywhere

    const int lane = tid & 63;
    const int w = tid >> 6;                          // wave 0..3
    const int l15 = lane & 15, l4 = lane >> 4;
    const int hl = w * 16 + l15;                     // hcol-local 0..63
    const int hcol = ch * 64 + hl;                   // global 0..127

    // ---- stage cx tile: 2 fire-and-forget global_load_lds_dwordx4 per wave ----
    // group g = p*4 + w holds teams brow + p*16 + w*4 + {0..3}; 1 KB linear write
    {
        #pragma unroll
        for (int p = 0; p < 2; ++p) {
            int team = brow + p * 16 + w * 4 + l4;
            load_lds16(cx + (size_t)team * 128 + ch * 64 + l15 * 4,
                       cxl + (p * 4 + w) * 260 + lane * 4);
        }
    }

    // ---- stage A = [inputs | hx] as bf16, XOR-swizzled: 2 passes x 1 row ----
    {
        const int r0 = tid >> 4, seg = tid & 15;     // rows r0, r0+16; 16 segs of 16 k
        const float* srcb = (seg < 8) ? inputs + seg * 16 : hx + (seg - 8) * 16;
        char* lbw = reinterpret_cast<char*>(Abf);
        const int swz = (r0 & 7) << 4;               // (row&7) invariant under +16
        #pragma unroll
        for (int p = 0; p < 2; ++p) {
            int r = p * 16 + r0;
            const float* src = srcb + (size_t)(brow + r) * 128;
            float4 v0 = *reinterpret_cast<const float4*>(src);
            float4 v1 = *reinterpret_cast<const float4*>(src + 4);
            float4 v2 = *reinterpret_cast<const float4*>(src + 8);
            float4 v3 = *reinterpret_cast<const float4*>(src + 12);
            int base = r * 512 + seg * 32;
            uint4 q0, q1;
            q0.x = cvtpk(v0.x, v0.y); q0.y = cvtpk(v0.z, v0.w);
            q0.z = cvtpk(v1.x, v1.y); q0.w = cvtpk(v1.z, v1.w);
            q1.x = cvtpk(v2.x, v2.y); q1.y = cvtpk(v2.z, v2.w);
            q1.z = cvtpk(v3.x, v3.y); q1.w = cvtpk(v3.z, v3.w);
            *reinterpret_cast<uint4*>(lbw + (base ^ swz)) = q0;
            *reinterpret_cast<uint4*>(lbw + ((base + 16) ^ swz)) = q1;
        }
        Wlds[tid] = W_out[tid];
        Wlds[256 + tid] = W_out[256 + tid];
        Wlds[512 + tid] = W_out[512 + tid];
    }

    // B fragment base: group G = ch*4 + w, contiguous 1KB per wave-load
    const unsigned short* bpg = Wpk + (size_t)(ch * 4 + w) * 16384 + lane * 8;
    const float bic = biasc[hcol];                   // -c*bi
    const float bfc = biasc[128 + hcol];             // -c*bf
    const float bgc = biasc[256 + hcol];             // +2c*bg
    const float boc = biasc[384 + hcol];             // -c*bo
    const int swzA = (l15 & 7) << 4;
    const int kf = l4 * 16;
    const char* pArow = reinterpret_cast<const char*>(Abf) + l15 * 512;

    f32x4 acc[2][4] = {};                            // [m][gate], 32 AGPRs

    __syncthreads();                                 // drains vmcnt too: cxl + Abf valid

    #pragma unroll
    for (int ks = 0; ks < 8; ++ks) {                 // K = 256 in steps of 32
        bf16x8 b0 = *(const bf16x8*)(bpg + ks * 512);
        bf16x8 b1 = *(const bf16x8*)(bpg + 4096 + ks * 512);
        bf16x8 b2 = *(const bf16x8*)(bpg + 8192 + ks * 512);
        bf16x8 b3 = *(const bf16x8*)(bpg + 12288 + ks * 512);
        const int ko = (ks * 64 + kf) ^ swzA;
        #pragma unroll
        for (int m = 0; m < 2; ++m) {
            bf16x8 af = *(const bf16x8*)(pArow + m * 8192 + ko);
            acc[m][0] = __builtin_amdgcn_mfma_f32_16x16x32_bf16(af, b0, acc[m][0], 0, 0, 0);
            acc[m][1] = __builtin_amdgcn_mfma_f32_16x16x32_bf16(af, b1, acc[m][1], 0, 0, 0);
            acc[m][2] = __builtin_amdgcn_mfma_f32_16x16x32_bf16(af, b2, acc[m][2], 0, 0, 0);
            acc[m][3] = __builtin_amdgcn_mfma_f32_16x16x32_bf16(af, b3, acc[m][3], 0, 0, 0);
        }
    }

    __syncthreads();                                 // all A reads done; LDS becomes Hf

    // ---- activations; h -> swizzled f32 [32][64] over Abf. cx from cxl. ----
    // C/D layout: col = l15 -> hcol, row = l4*4 + j -> team-local
    {
        char* lb = reinterpret_cast<char*>(Abf);
        #pragma unroll
        for (int m = 0; m < 2; ++m) {
            #pragma unroll
            for (int j = 0; j < 4; ++j) {
                float cxv = cxl[(m * 4 + l4) * 260 + j * 64 + hl];
                float si = rcp_(1.0f + exp2_(fmaf(acc[m][0][j], -LOG2E, bic)));
                float sf = rcp_(1.0f + exp2_(fmaf(acc[m][1][j], -LOG2E, bfc)));
                float tg = fmaf(-2.0f, rcp_(1.0f + exp2_(fmaf(acc[m][2][j], 2.0f * LOG2E, bgc))), 1.0f);
                float so = rcp_(1.0f + exp2_(fmaf(acc[m][3][j], -LOG2E, boc)));
                float cn = fmaf(sf, cxv, si * tg);
                float tc = fmaf(-2.0f, rcp_(1.0f + exp2_(cn * (2.0f * LOG2E))), 1.0f);
                float hn = so * tc;
                int t = m * 16 + l4 * 4 + j;
                *reinterpret_cast<float*>(lb + ((t * 256 + hl * 4) ^ ((t & 7) << 4))) = hn;
            }
        }
    }
    __syncthreads();

    // ---- fused partial proj: 8 threads/team, 8 hcols each, 6 partial outputs ----
    {
        int tl = tid >> 3, sub = tid & 7;            // team-local 0..31, sub 0..7
        const char* lb = reinterpret_cast<const char*>(Abf);
        int hbase = tl * 256 + sub * 32;
        int hswz = (tl & 7) << 4;
        float a0 = 0.f, a1 = 0.f, a2 = 0.f, a3 = 0.f, a4 = 0.f, a5 = 0.f;
        #pragma unroll
        for (int c = 0; c < 2; ++c) {
            f32x4 h4 = *reinterpret_cast<const f32x4*>(lb + ((hbase + c * 16) ^ hswz));
            #pragma unroll
            for (int i = 0; i < 4; ++i) {
                float h = h4[i];
                int col = ch * 64 + sub * 8 + c * 4 + i;     // global hcol 0..127
                a0 += h * Wlds[col];       a1 += h * Wlds[256 + col]; a2 += h * Wlds[512 + col];
                a3 += h * Wlds[128 + col]; a4 += h * Wlds[384 + col]; a5 += h * Wlds[640 + col];
            }
        }
        a0 += __shfl_xor(a0, 1); a1 += __shfl_xor(a1, 1); a2 += __shfl_xor(a2, 1);
        a3 += __shfl_xor(a3, 1); a4 += __shfl_xor(a4, 1); a5 += __shfl_xor(a5, 1);
        a0 += __shfl_xor(a0, 2); a1 += __shfl_xor(a1, 2); a2 += __shfl_xor(a2, 2);
        a3 += __shfl_xor(a3, 2); a4 += __shfl_xor(a4, 2); a5 += __shfl_xor(a5, 2);
        a0 += __shfl_xor(a0, 4); a1 += __shfl_xor(a1, 4); a2 += __shfl_xor(a2, 4);
        a3 += __shfl_xor(a3, 4); a4 += __shfl_xor(a4, 4); a5 += __shfl_xor(a5, 4);
        int team = brow + tl;
        if (sub == 0) {
            float4* o = reinterpret_cast<float4*>(projP + (size_t)team * 16 + ch * 8);
            o[0] = make_float4(a0, a1, a2, a2);      // home partial
            o[1] = make_float4(a3, a4, a5, a5);      // away partial
        }
    }
}

// ---------------- match head: sum half-partials; logits + b_out ; softmax ----------------
__global__ __launch_bounds__(256) void match_kernel(
    const int* __restrict__ matches, const float* __restrict__ projP,
    const float* __restrict__ b_out, float* __restrict__ out)
{
    int m = blockIdx.x * 256 + threadIdx.x;
    if (m >= NUM_MATCHES) return;
    int2 mi = reinterpret_cast<const int2*>(matches)[m];
    const float4* pp = reinterpret_cast<const float4*>(projP);
    float4 h0 = pp[(size_t)mi.x * 4 + 0];            // half0 home
    float4 h1 = pp[(size_t)mi.x * 4 + 2];            // half1 home
    float4 a0 = pp[(size_t)mi.y * 4 + 1];            // half0 away
    float4 a1 = pp[(size_t)mi.y * 4 + 3];            // half1 away
    float l0 = h0.x + h1.x + a0.x + a1.x + b_out[0];
    float l1 = h0.y + h1.y + a0.y + a1.y + b_out[1];
    float l2 = h0.z + h1.z + a0.z + a1.z + b_out[2];
    float mx = fmaxf(l0, fmaxf(l1, l2));
    float e0 = __expf(l0 - mx), e1 = __expf(l1 - mx), e2 = __expf(l2 - mx);
    float inv = 1.0f / (e0 + e1 + e2);
    out[3 * m + 0] = e0 * inv;
    out[3 * m + 1] = e1 * inv;
    out[3 * m + 2] = e2 * inv;
}

extern "C" void kernel_launch(void* const* d_in, const int* in_sizes, int n_in,
                              void* d_out, int out_size, void* d_ws, size_t ws_size,
                              hipStream_t stream) {
    const float* inputs = (const float*)d_in[0];
    const float* hx     = (const float*)d_in[1];
    const float* cx     = (const float*)d_in[2];
    const int*   matches= (const int*)d_in[3];
    const float* W_ih   = (const float*)d_in[4];
    const float* W_hh   = (const float*)d_in[5];
    const float* b_ih   = (const float*)d_in[6];
    const float* b_hh   = (const float*)d_in[7];
    const float* W_out  = (const float*)d_in[8];
    const float* b_out  = (const float*)d_in[9];
    float* out = (float*)d_out;

    char* ws = (char*)d_ws;
    unsigned short* Wpk  = (unsigned short*)ws;                  // 256 KB fragment-major
    float* biasc         = (float*)(ws + 262144);                // 2 KB
    float* projP         = (float*)(ws + (1 << 20));             // 100000*16*4 = 6.4 MB

    prep_kernel <<<512, 256, 0, stream>>>(W_ih, W_hh, b_ih, b_hh, Wpk, biasc);
    lstm_kernel <<<NWG, 256, 0, stream>>>(inputs, hx, cx, Wpk, biasc, W_out, projP);
    match_kernel<<<(NUM_MATCHES + 255) / 256, 256, 0, stream>>>(matches, projP, b_out, out);
}